// Round 1
// baseline (702.299 us; speedup 1.0000x reference)
//
#include <hip/hip_runtime.h>
#include <hip/hip_bf16.h>

// Problem constants
#define B_   4
#define C_   256
#define N_   3136
#define QT_  196     // N/16 q-tiles per batch
#define NKV_ 98      // N/32 kv tiles

typedef __attribute__((ext_vector_type(8))) short bf16x8;
typedef __attribute__((ext_vector_type(4))) float f32x4;

#define LOG2E  1.4426950408889634f
#define SCALE2 (LOG2E / 16.0f)     // (1/sqrt(C)) * log2(e)

// ---- async global->LDS 16B helper (dest must be linear: base + lane*16) ----
__device__ __forceinline__ void gld16(const void* g, void* l) {
  __builtin_amdgcn_global_load_lds(
      (const __attribute__((address_space(1))) unsigned int*)g,
      (__attribute__((address_space(3))) unsigned int*)l, 16, 0, 0);
}

// ---- [b][c][n] f32  ->  [b][n][c] bf16 tokens ----
__global__ __launch_bounds__(256) void transpose_tok_kernel(
    const float* __restrict__ src, __hip_bfloat16* __restrict__ dst) {
  __shared__ float tile[32][33];
  const int b  = blockIdx.z;
  const int n0 = blockIdx.x * 32;
  const int c0 = blockIdx.y * 32;
  const int tx = threadIdx.x & 31;
  const int ty = threadIdx.x >> 5;     // 0..7
  const float* s = src + (size_t)b * C_ * N_;
#pragma unroll
  for (int i = 0; i < 4; ++i) {
    int c = c0 + ty + i * 8;
    tile[ty + i * 8][tx] = s[(size_t)c * N_ + n0 + tx];
  }
  __syncthreads();
  __hip_bfloat16* d = dst + (size_t)b * N_ * C_;
#pragma unroll
  for (int i = 0; i < 4; ++i) {
    int n = n0 + ty + i * 8;
    d[(size_t)n * C_ + c0 + tx] = __float2bfloat16(tile[tx][ty + i * 8]);
  }
}

// ---- f32 -> bf16 flat convert (weights) ----
__global__ __launch_bounds__(256) void cvt_bf16_kernel(
    const float* __restrict__ src, __hip_bfloat16* __restrict__ dst, int n) {
  int i = blockIdx.x * 256 + threadIdx.x;
  if (i < n) dst[i] = __float2bfloat16(src[i]);
}

// ---- vT[b][c][n] = sum_k Wv[c][k] * f[b][n][k] + bv[c]   (written transposed) ----
__global__ __launch_bounds__(256) void v_linear_kernel(
    const __hip_bfloat16* __restrict__ fb,   // [B][N][C]
    const __hip_bfloat16* __restrict__ Wv,   // [C][C] bf16
    const float* __restrict__ bv,
    __hip_bfloat16* __restrict__ vT)         // [B][C][N]
{
  const int b    = blockIdx.z;
  const int cblk = blockIdx.y;
  const int nblk = blockIdx.x;
  const int wave = threadIdx.x >> 6;
  const int lane = threadIdx.x & 63;
  const int qt = lane & 15, g = lane >> 4;
  const int c0 = cblk * 64 + wave * 16;
  const int n0 = nblk * 64;
  const __hip_bfloat16* fbb = fb + (size_t)b * N_ * C_;
  f32x4 acc[4];
#pragma unroll
  for (int j = 0; j < 4; ++j) acc[j] = (f32x4){0.f, 0.f, 0.f, 0.f};
#pragma unroll
  for (int kk = 0; kk < 8; ++kk) {
    int ko = kk * 32 + g * 8;
    bf16x8 a = *(const bf16x8*)(Wv + (size_t)(c0 + qt) * C_ + ko);
#pragma unroll
    for (int j = 0; j < 4; ++j) {
      bf16x8 bb = *(const bf16x8*)(fbb + (size_t)(n0 + j * 16 + qt) * C_ + ko);
      acc[j] = __builtin_amdgcn_mfma_f32_16x16x32_bf16(a, bb, acc[j], 0, 0, 0);
    }
  }
  __hip_bfloat16* out = vT + (size_t)b * C_ * N_;
#pragma unroll
  for (int j = 0; j < 4; ++j)
#pragma unroll
    for (int r = 0; r < 4; ++r) {
      int c = c0 + 4 * g + r;
      int n = n0 + j * 16 + qt;
      out[(size_t)c * N_ + n] = __float2bfloat16(acc[j][r] + bv[c]);
    }
}

// ---- flash attention with 4-way KV split; writes unnormalized partials ----
__global__ __launch_bounds__(512) void attn_kernel(
    const __hip_bfloat16* __restrict__ qb,   // [B][N][C]
    const __hip_bfloat16* __restrict__ kb,   // [B][N][C]
    const __hip_bfloat16* __restrict__ vT,   // [B][C][N]
    const float* __restrict__ mask,          // [N][N]
    float* __restrict__ pO,                  // [B][196][4][16][256]
    float* __restrict__ pML)                 // [B][196][4][2][16]
{
  __shared__ __hip_bfloat16 Kl[32 * 256];   // 16KB (xor-swizzled rows of 512B)
  __shared__ __hip_bfloat16 Vl[256 * 32];   // 16KB V^T (xor-swizzled rows of 64B)
  __shared__ __hip_bfloat16 Pl[8][512];     // per-wave P tiles

  const int b     = blockIdx.z;
  const int chunk = blockIdx.y;
  const int wave  = threadIdx.x >> 6;
  const int lane  = threadIdx.x & 63;
  const int qt = lane & 15, g = lane >> 4;
  const int qtile = blockIdx.x * 8 + wave;
  const bool valid = qtile < QT_;
  const int q0 = qtile * 16;
  const int t0 = (chunk * NKV_) >> 2;
  const int t1 = ((chunk + 1) * NKV_) >> 2;

  const __hip_bfloat16* qbb = qb + (size_t)b * N_ * C_;
  const __hip_bfloat16* kbb = kb + (size_t)b * N_ * C_;
  const __hip_bfloat16* vbb = vT + (size_t)b * C_ * N_;

  bf16x8 qa[8];
  if (valid) {
#pragma unroll
    for (int kk = 0; kk < 8; ++kk)
      qa[kk] = *(const bf16x8*)(qbb + (size_t)(q0 + qt) * C_ + kk * 32 + g * 8);
  }

  f32x4 o[16];
#pragma unroll
  for (int i = 0; i < 16; ++i) o[i] = (f32x4){0.f, 0.f, 0.f, 0.f};
  float mrow[4] = {-1e30f, -1e30f, -1e30f, -1e30f};
  float lrow[4] = {0.f, 0.f, 0.f, 0.f};

  for (int t = t0; t < t1; ++t) {
    const int k0 = t * 32;
    __syncthreads();            // previous tile fully consumed
    {
      const int tid = threadIdx.x;
      // K tile: rows = 32 keys x 512B; LDS linear, global source pre-swizzled
#pragma unroll
      for (int i = 0; i < 2; ++i) {
        int off = (tid + i * 512) * 16;
        int row = off >> 9;
        int cb  = (off & 511) ^ ((row & 7) << 4);
        gld16((const char*)(kbb + (size_t)(k0 + row) * C_) + cb, (char*)Kl + off);
      }
      // V^T tile: 256 rows x 64B
#pragma unroll
      for (int i = 0; i < 2; ++i) {
        int off = (tid + i * 512) * 16;
        int row = off >> 6;
        int cb  = (off & 63) ^ ((row & 3) << 4);
        gld16((const char*)(vbb + (size_t)row * N_ + k0) + cb, (char*)Vl + off);
      }
    }
    __syncthreads();            // staged data visible
    if (!valid) continue;

    // ---- S = Q @ K^T (two 16x16 tiles over 32 keys) ----
    f32x4 s0 = (f32x4){0.f,0.f,0.f,0.f}, s1 = (f32x4){0.f,0.f,0.f,0.f};
#pragma unroll
    for (int kk = 0; kk < 8; ++kk) {
      int cb = (kk * 64 + g * 16) ^ ((qt & 7) << 4);   // (16+qt)&7 == qt&7
      bf16x8 kf0 = *(const bf16x8*)((const char*)Kl + qt * 512 + cb);
      s0 = __builtin_amdgcn_mfma_f32_16x16x32_bf16(qa[kk], kf0, s0, 0, 0, 0);
      bf16x8 kf1 = *(const bf16x8*)((const char*)Kl + (16 + qt) * 512 + cb);
      s1 = __builtin_amdgcn_mfma_f32_16x16x32_bf16(qa[kk], kf1, s1, 0, 0, 0);
    }

    // ---- online softmax (exp2 domain), mask added here ----
    float fr[4];
#pragma unroll
    for (int r = 0; r < 4; ++r) {
      size_t mbase = (size_t)(q0 + 4 * g + r) * N_ + k0;
      float v0 = s0[r] * SCALE2 + mask[mbase + qt] * LOG2E;
      float v1 = s1[r] * SCALE2 + mask[mbase + 16 + qt] * LOG2E;
      float mx = fmaxf(v0, v1);
#pragma unroll
      for (int d = 1; d < 16; d <<= 1) mx = fmaxf(mx, __shfl_xor(mx, d));
      float mn = fmaxf(mrow[r], mx);
      fr[r] = exp2f(mrow[r] - mn);
      mrow[r] = mn;
      float p0 = exp2f(v0 - mn), p1 = exp2f(v1 - mn);
      float ps = p0 + p1;
#pragma unroll
      for (int d = 1; d < 16; d <<= 1) ps += __shfl_xor(ps, d);
      lrow[r] = lrow[r] * fr[r] + ps;
      s0[r] = p0; s1[r] = p1;
    }
#pragma unroll
    for (int ct = 0; ct < 16; ++ct) {
      o[ct][0] *= fr[0]; o[ct][1] *= fr[1]; o[ct][2] *= fr[2]; o[ct][3] *= fr[3];
    }

    // ---- P -> LDS (bf16, xor-swizzled), then A-frag read ----
    char* pw = (char*)&Pl[wave][0];
#pragma unroll
    for (int r = 0; r < 4; ++r) {
      int q = 4 * g + r;                 // (q&3)==r
      *(__hip_bfloat16*)(pw + q * 64 + ((qt * 2) ^ (r << 4)))      = __float2bfloat16(s0[r]);
      *(__hip_bfloat16*)(pw + q * 64 + ((32 + qt * 2) ^ (r << 4))) = __float2bfloat16(s1[r]);
    }
    bf16x8 pa = *(const bf16x8*)(pw + qt * 64 + ((g * 16) ^ ((qt & 3) << 4)));

    // ---- O += P @ V ----
#pragma unroll
    for (int ct = 0; ct < 16; ++ct) {
      int row = ct * 16 + qt;
      int cb  = (g * 16) ^ ((row & 3) << 4);
      bf16x8 vf = *(const bf16x8*)((const char*)Vl + row * 64 + cb);
      o[ct] = __builtin_amdgcn_mfma_f32_16x16x32_bf16(pa, vf, o[ct], 0, 0, 0);
    }
  }

  if (valid) {
    float* po = pO + ((((size_t)b * QT_ + qtile) * 4 + chunk) * 16) * 256;
#pragma unroll
    for (int ct = 0; ct < 16; ++ct)
#pragma unroll
      for (int r = 0; r < 4; ++r)
        po[(4 * g + r) * 256 + ct * 16 + qt] = o[ct][r];
    if (qt == 0) {
      float* pml = pML + (((size_t)b * QT_ + qtile) * 4 + chunk) * 32;
#pragma unroll
      for (int r = 0; r < 4; ++r) {
        pml[4 * g + r]      = mrow[r];
        pml[16 + 4 * g + r] = lrow[r];
      }
    }
  }
}

// ---- combine 4 KV-chunk partials; refined = O/l + f  -> bf16 [b][n][c] ----
__global__ __launch_bounds__(256) void combine_kernel(
    const float* __restrict__ pO, const float* __restrict__ pML,
    const __hip_bfloat16* __restrict__ fb,
    __hip_bfloat16* __restrict__ ref)
{
  const int b = blockIdx.y;
  const int qtile = blockIdx.x;
  const int tid = threadIdx.x;
  const int row = tid >> 4;
  const int c0v = (tid & 15) * 16;
  const float* pml = pML + (((size_t)b * QT_ + qtile) * 4) * 32;
  float mc[4], lc[4];
#pragma unroll
  for (int c = 0; c < 4; ++c) { mc[c] = pml[c * 32 + row]; lc[c] = pml[c * 32 + 16 + row]; }
  float M = fmaxf(fmaxf(mc[0], mc[1]), fmaxf(mc[2], mc[3]));
  float w[4]; float L = 0.f;
#pragma unroll
  for (int c = 0; c < 4; ++c) { w[c] = exp2f(mc[c] - M); L += w[c] * lc[c]; }
  const float invL = 1.f / L;
  const float* po = pO + ((((size_t)b * QT_ + qtile) * 4) * 16) * 256;
  const int n = qtile * 16 + row;
  const __hip_bfloat16* f = fb + ((size_t)b * N_ + n) * C_;
  __hip_bfloat16* rf = ref + ((size_t)b * N_ + n) * C_;
  struct alignas(8) bh4 { __hip_bfloat16 x[4]; };
#pragma unroll
  for (int v4 = 0; v4 < 4; ++v4) {
    int cc = c0v + v4 * 4;
    f32x4 acc = (f32x4){0.f, 0.f, 0.f, 0.f};
#pragma unroll
    for (int c = 0; c < 4; ++c) {
      f32x4 x = *(const f32x4*)(po + ((size_t)c * 16 + row) * 256 + cc);
      acc += x * w[c];
    }
    bh4 tmp;
#pragma unroll
    for (int j = 0; j < 4; ++j)
      tmp.x[j] = __float2bfloat16(acc[j] * invL + __bfloat162float(f[cc + j]));
    *(bh4*)(rf + cc) = tmp;
  }
}

// ---- out[c][n] = Wl[:, :256] @ refined^T + Wl[:, 256:] @ f^T + bl ----
__global__ __launch_bounds__(256) void out_linear_kernel(
    const __hip_bfloat16* __restrict__ refb,
    const __hip_bfloat16* __restrict__ fb,
    const __hip_bfloat16* __restrict__ Wl,   // [256][512]
    const float* __restrict__ bl,
    float* __restrict__ out)                 // + b*4*C*N + c*N + n (pre-offset by slot)
{
  const int b    = blockIdx.z;
  const int cblk = blockIdx.y;
  const int nblk = blockIdx.x;
  const int wave = threadIdx.x >> 6;
  const int lane = threadIdx.x & 63;
  const int qt = lane & 15, g = lane >> 4;
  const int c0 = cblk * 64 + wave * 16;
  const int n0 = nblk * 64;
  const __hip_bfloat16* rb  = refb + (size_t)b * N_ * C_;
  const __hip_bfloat16* fbb = fb  + (size_t)b * N_ * C_;
  f32x4 acc[4];
#pragma unroll
  for (int j = 0; j < 4; ++j) acc[j] = (f32x4){0.f, 0.f, 0.f, 0.f};
#pragma unroll
  for (int kk = 0; kk < 8; ++kk) {
    int ko = kk * 32 + g * 8;
    bf16x8 a = *(const bf16x8*)(Wl + (size_t)(c0 + qt) * 512 + ko);
#pragma unroll
    for (int j = 0; j < 4; ++j) {
      bf16x8 bb = *(const bf16x8*)(rb + (size_t)(n0 + j * 16 + qt) * C_ + ko);
      acc[j] = __builtin_amdgcn_mfma_f32_16x16x32_bf16(a, bb, acc[j], 0, 0, 0);
    }
  }
#pragma unroll
  for (int kk = 0; kk < 8; ++kk) {
    int ko = kk * 32 + g * 8;
    bf16x8 a = *(const bf16x8*)(Wl + (size_t)(c0 + qt) * 512 + 256 + ko);
#pragma unroll
    for (int j = 0; j < 4; ++j) {
      bf16x8 bb = *(const bf16x8*)(fbb + (size_t)(n0 + j * 16 + qt) * C_ + ko);
      acc[j] = __builtin_amdgcn_mfma_f32_16x16x32_bf16(a, bb, acc[j], 0, 0, 0);
    }
  }
  float* ob = out + (size_t)b * 4 * C_ * N_;
#pragma unroll
  for (int j = 0; j < 4; ++j)
#pragma unroll
    for (int r = 0; r < 4; ++r) {
      int c = c0 + 4 * g + r;
      int n = n0 + j * 16 + qt;
      ob[(size_t)c * N_ + n] = acc[j][r] + bl[c];
    }
}

extern "C" void kernel_launch(void* const* d_in, const int* in_sizes, int n_in,
                              void* d_out, int out_size, void* d_ws, size_t ws_size,
                              hipStream_t stream) {
  (void)in_sizes; (void)n_in; (void)out_size; (void)ws_size;
  const float* feat0 = (const float*)d_in[0];
  const float* feat1 = (const float*)d_in[1];
  const float* feat2 = (const float*)d_in[2];
  const float* feat3 = (const float*)d_in[3];
  const float* mask  = (const float*)d_in[7];
  const float* Wv    = (const float*)d_in[8];
  const float* bv    = (const float*)d_in[9];
  const float* Wl    = (const float*)d_in[10];
  const float* bl    = (const float*)d_in[11];
  float* out = (float*)d_out;

  const size_t TOKB = (size_t)B_ * N_ * C_ * 2;  // 6,422,528
  char* w = (char*)d_ws;
  __hip_bfloat16* q0   = (__hip_bfloat16*)(w);
  __hip_bfloat16* f1   = (__hip_bfloat16*)(w + TOKB);
  __hip_bfloat16* f2   = (__hip_bfloat16*)(w + 2 * TOKB);
  __hip_bfloat16* f3   = (__hip_bfloat16*)(w + 3 * TOKB);
  __hip_bfloat16* vT   = (__hip_bfloat16*)(w + 4 * TOKB);
  __hip_bfloat16* refA = (__hip_bfloat16*)(w + 5 * TOKB);
  __hip_bfloat16* refB = (__hip_bfloat16*)(w + 6 * TOKB);
  char* w2 = w + 7 * TOKB;
  __hip_bfloat16* Wv_bf = (__hip_bfloat16*)(w2);
  __hip_bfloat16* Wl_bf = (__hip_bfloat16*)(w2 + 131072);
  float* pO  = (float*)(w2 + 131072 + 262144);
  float* pML = (float*)(w2 + 131072 + 262144 + (size_t)B_ * QT_ * 4 * 16 * 256 * 4);

  dim3 tb(256);
  dim3 tg(98, 8, 4);
  transpose_tok_kernel<<<tg, tb, 0, stream>>>(feat0, q0);
  transpose_tok_kernel<<<tg, tb, 0, stream>>>(feat1, f1);
  transpose_tok_kernel<<<tg, tb, 0, stream>>>(feat2, f2);
  transpose_tok_kernel<<<tg, tb, 0, stream>>>(feat3, f3);
  cvt_bf16_kernel<<<dim3((C_ * C_ + 255) / 256), tb, 0, stream>>>(Wv, Wv_bf, C_ * C_);
  cvt_bf16_kernel<<<dim3((C_ * 2 * C_ + 255) / 256), tb, 0, stream>>>(Wl, Wl_bf, C_ * 2 * C_);

  // slot 0: feat0 passthrough
  for (int b = 0; b < B_; ++b)
    hipMemcpyAsync(out + (size_t)b * 4 * C_ * N_, feat0 + (size_t)b * C_ * N_,
                   (size_t)C_ * N_ * sizeof(float), hipMemcpyDeviceToDevice, stream);

  const __hip_bfloat16* fs[3] = {f1, f2, f3};
  __hip_bfloat16* refs[2] = {refA, refB};
  const __hip_bfloat16* q = q0;
  for (int s = 0; s < 3; ++s) {
    const __hip_bfloat16* f = fs[s];
    v_linear_kernel<<<dim3(49, 4, 4), tb, 0, stream>>>(f, Wv_bf, bv, vT);
    attn_kernel<<<dim3(25, 4, 4), dim3(512), 0, stream>>>(q, f, vT, mask, pO, pML);
    combine_kernel<<<dim3(196, 4), tb, 0, stream>>>(pO, pML, f, refs[s & 1]);
    out_linear_kernel<<<dim3(49, 4, 4), tb, 0, stream>>>(refs[s & 1], f, Wl_bf, bl,
                                                         out + (size_t)(s + 1) * C_ * N_);
    q = refs[s & 1];
  }
}